// Round 7
// baseline (4365.371 us; speedup 1.0000x reference)
//
#include <hip/hip_runtime.h>

// 2-layer LSTM encoder, v7: barrier-free wave-local recurrences.
//
// ROUND-6 FINDING: step time ~600-720ns was invariant across 4 structures ->
// the bottleneck is the fixed per-step latency chain of CROSS-WAVE hand-offs
// (LDS round-trips + barrier wakeups), not any throughput limit.
//
// v7: 64 blocks (1 per batch element) x 128 threads (2 waves).
//  wave 0 = layer 1. lane j = unit j. ALL 4 gates of unit j computed in-lane
//    (272 MACs as float2 pk-fma chains), c1/h1[j] in-lane. h1 redistributed
//    via same-wave LDS (1 ds_write_b32 + 16 broadcast ds_read_b128), ordered
//    by lgkmcnt -- NO barriers anywhere in the loop.
//  wave 1 = layer 2, runs one step behind. lane = (unit j = lane>>1,
//    half = lane&1); each lane does the 4 gates of unit j over half of
//    K=96; halves combined with __shfl_xor(.,1) (DPP, no LDS). h2 recurrence
//    wave-local via 2-slot ring.
//  l1 -> l2 hand-off: depth-4 h1 ring + flags, volatile + threadfence_block
//    (producer-consumer, no __syncthreads). Backpressure: l1 waits
//    flags[1] >= n-3 before overwriting slot n&3; l2 signals consumption
//    right after copying h1 to registers.

#define BATCH 64
#define T 4096
#define H1 64
#define H2 32
#define L2E 1.442695040888963f

typedef __attribute__((ext_vector_type(2))) float v2f;

__device__ __forceinline__ float fast_rcp(float v){ return __builtin_amdgcn_rcpf(v); }
__device__ __forceinline__ float sigm(float s){ return fast_rcp(1.0f + exp2f(-L2E*s)); }
__device__ __forceinline__ float tanh_(float s){ return 1.0f - 2.0f*fast_rcp(exp2f(2.0f*L2E*s) + 1.0f); }
__device__ __forceinline__ v2f fma2(v2f a, v2f b, v2f c){ return __builtin_elementwise_fma(a, b, c); }
__device__ __forceinline__ v2f mk2(float a, float b){ v2f r; r.x = a; r.y = b; return r; }

__global__ __launch_bounds__(128)
__attribute__((amdgpu_waves_per_eu(1, 1)))
void lstm2_v7(const float* __restrict__ x,
              const float* __restrict__ W_ih1, const float* __restrict__ W_hh1,
              const float* __restrict__ b_ih1, const float* __restrict__ b_hh1,
              const float* __restrict__ W_ih2, const float* __restrict__ W_hh2,
              const float* __restrict__ b_ih2, const float* __restrict__ b_hh2,
              float* __restrict__ out)
{
    const int b = blockIdx.x, tid = threadIdx.x;
    const int wave = tid >> 6, lane = tid & 63;

    __shared__ __align__(16) float h1ring[4][H1];   // slot n&3 holds h1(n)
    __shared__ __align__(16) float h2ring[2][H2];   // slot m&1 holds h2(m)
    __shared__ int flags[2];                        // [0]: l1 published n+1
                                                    // [1]: l2 consumed m+1
    if (tid < H1) h1ring[3][tid] = 0.0f;            // h1(-1) = 0
    if (tid < H2) h2ring[1][tid] = 0.0f;            // h2(-1) = 0
    if (tid < 2)  flags[tid] = 0;
    __syncthreads();                                // only barrier in the kernel

    volatile int* f1 = &flags[0];
    volatile int* f2 = &flags[1];

    if (wave == 0) {
        // ================= LAYER 1 =================
        const int j = lane;
        v2f wlo[4][16], whi[4][16], wxlo[4], wxhi[4];
        float bias[4];
        #pragma unroll
        for (int t = 0; t < 4; ++t) {
            const float* r = W_hh1 + (size_t)(64 * t + j) * H1;
            #pragma unroll
            for (int kk = 0; kk < 16; ++kk) {
                float4 v = *(const float4*)(r + 4 * kk);
                wlo[t][kk] = mk2(v.x, v.y);
                whi[t][kk] = mk2(v.z, v.w);
            }
            float4 wxv = *(const float4*)(W_ih1 + (size_t)(64 * t + j) * 4);
            wxlo[t] = mk2(wxv.x, wxv.y);
            wxhi[t] = mk2(wxv.z, wxv.w);
            bias[t] = b_ih1[64 * t + j] + b_hh1[64 * t + j];
        }
        float c1 = 0.0f;
        const float4* xptr = (const float4*)(x + (size_t)b * T * 4);
        float4 xc = xptr[0];

        for (int n = 0; n < T; ++n) {
            float4 xn = xptr[(n + 1 < T) ? (n + 1) : (T - 1)];   // prefetch
            if (n >= 4) { while (*f2 < n - 3) { } }              // backpressure
            const float4* hv = (const float4*)h1ring[(n + 3) & 3]; // h1(n-1)
            float4 hbuf[16];
            #pragma unroll
            for (int kk = 0; kk < 16; ++kk) hbuf[kk] = hv[kk];

            v2f aP[4], aQ[4];
            v2f xlo = mk2(xc.x, xc.y), xhi = mk2(xc.z, xc.w);
            #pragma unroll
            for (int t = 0; t < 4; ++t) {
                aP[t] = fma2(wxlo[t], xlo, mk2(bias[t], 0.0f));
                aQ[t] = fma2(wxhi[t], xhi, mk2(0.0f, 0.0f));
            }
            #pragma unroll
            for (int kk = 0; kk < 16; ++kk) {
                v2f hlo = mk2(hbuf[kk].x, hbuf[kk].y);
                v2f hhi = mk2(hbuf[kk].z, hbuf[kk].w);
                #pragma unroll
                for (int t = 0; t < 4; ++t) {
                    aP[t] = fma2(wlo[t][kk], hlo, aP[t]);
                    aQ[t] = fma2(whi[t][kk], hhi, aQ[t]);
                }
            }
            float p0 = (aP[0].x + aQ[0].x) + (aP[0].y + aQ[0].y);
            float p1 = (aP[1].x + aQ[1].x) + (aP[1].y + aQ[1].y);
            float p2 = (aP[2].x + aQ[2].x) + (aP[2].y + aQ[2].y);
            float p3 = (aP[3].x + aQ[3].x) + (aP[3].y + aQ[3].y);
            float gi = sigm(p0), gf = sigm(p1), gg = tanh_(p2), go = sigm(p3);
            c1 = fmaf(gf, c1, gi * gg);
            float h = go * tanh_(c1);

            __threadfence_block();          // poll/reads ordered before write
            h1ring[n & 3][j] = h;
            __threadfence_block();          // write visible before flag
            if (lane == 0) *f1 = n + 1;
            xc = xn;
        }
    } else {
        // ================= LAYER 2 =================
        const int j = lane >> 1, half = lane & 1;
        v2f wi[4][16], wh[4][8];
        float bias[4];
        #pragma unroll
        for (int t = 0; t < 4; ++t) {
            const int g = 32 * t + j;
            const float* ri = W_ih2 + (size_t)g * H1 + 32 * half;
            #pragma unroll
            for (int kk = 0; kk < 8; ++kk) {
                float4 v = *(const float4*)(ri + 4 * kk);
                wi[t][2 * kk]     = mk2(v.x, v.y);
                wi[t][2 * kk + 1] = mk2(v.z, v.w);
            }
            const float* rh = W_hh2 + (size_t)g * H2 + 16 * half;
            #pragma unroll
            for (int kk = 0; kk < 4; ++kk) {
                float4 v = *(const float4*)(rh + 4 * kk);
                wh[t][2 * kk]     = mk2(v.x, v.y);
                wh[t][2 * kk + 1] = mk2(v.z, v.w);
            }
            bias[t] = half ? 0.0f : (b_ih2[g] + b_hh2[g]);
        }
        float c2 = 0.0f;
        float* outb = out + (size_t)b * T * H2;

        for (int m = 0; m < T; ++m) {
            while (*f1 < m + 1) { }                 // wait for h1(m)
            __threadfence_block();                  // no hoisting reads above
            const float4* h1v = (const float4*)h1ring[m & 3] + 8 * half;
            const float4* h2v = (const float4*)h2ring[(m + 1) & 1] + 4 * half;
            float4 A[8], Bq[4];
            #pragma unroll
            for (int kk = 0; kk < 8; ++kk) A[kk] = h1v[kk];
            #pragma unroll
            for (int kk = 0; kk < 4; ++kk) Bq[kk] = h2v[kk];
            __threadfence_block();                  // reads done ...
            if (lane == 0) *f2 = m + 1;             // ... release slot early

            v2f aP[4], aQ[4];
            #pragma unroll
            for (int t = 0; t < 4; ++t) {
                aP[t] = mk2(bias[t], 0.0f);
                aQ[t] = mk2(0.0f, 0.0f);
            }
            #pragma unroll
            for (int kk = 0; kk < 8; ++kk) {
                v2f lo = mk2(A[kk].x, A[kk].y), hi = mk2(A[kk].z, A[kk].w);
                #pragma unroll
                for (int t = 0; t < 4; ++t) {
                    aP[t] = fma2(wi[t][2 * kk], lo, aP[t]);
                    aQ[t] = fma2(wi[t][2 * kk + 1], hi, aQ[t]);
                }
            }
            #pragma unroll
            for (int kk = 0; kk < 4; ++kk) {
                v2f lo = mk2(Bq[kk].x, Bq[kk].y), hi = mk2(Bq[kk].z, Bq[kk].w);
                #pragma unroll
                for (int t = 0; t < 4; ++t) {
                    aP[t] = fma2(wh[t][2 * kk], lo, aP[t]);
                    aQ[t] = fma2(wh[t][2 * kk + 1], hi, aQ[t]);
                }
            }
            float ph[4];
            #pragma unroll
            for (int t = 0; t < 4; ++t)
                ph[t] = (aP[t].x + aQ[t].x) + (aP[t].y + aQ[t].y);
            float p0 = ph[0] + __shfl_xor(ph[0], 1, 64);   // DPP quad_perm
            float p1 = ph[1] + __shfl_xor(ph[1], 1, 64);
            float p2 = ph[2] + __shfl_xor(ph[2], 1, 64);
            float p3 = ph[3] + __shfl_xor(ph[3], 1, 64);
            float gi = sigm(p0), gf = sigm(p1), gg = tanh_(p2), go = sigm(p3);
            c2 = fmaf(gf, c2, gi * gg);
            float h = go * tanh_(c2);
            if (half == 0) {
                h2ring[m & 1][j] = h;
                outb[(size_t)m * H2 + j] = h;
            }
        }
    }
}

extern "C" void kernel_launch(void* const* d_in, const int* in_sizes, int n_in,
                              void* d_out, int out_size, void* d_ws, size_t ws_size,
                              hipStream_t stream) {
    const float* x     = (const float*)d_in[0];
    const float* W_ih1 = (const float*)d_in[1];
    const float* W_hh1 = (const float*)d_in[2];
    const float* b_ih1 = (const float*)d_in[3];
    const float* b_hh1 = (const float*)d_in[4];
    const float* W_ih2 = (const float*)d_in[5];
    const float* W_hh2 = (const float*)d_in[6];
    const float* b_ih2 = (const float*)d_in[7];
    const float* b_hh2 = (const float*)d_in[8];
    float* out = (float*)d_out;

    lstm2_v7<<<dim3(BATCH), dim3(128), 0, stream>>>(
        x, W_ih1, W_hh1, b_ih1, b_hh1, W_ih2, W_hh2, b_ih2, b_hh2, out);
}